// Round 10
// baseline (345.199 us; speedup 1.0000x reference)
//
#include <hip/hip_runtime.h>

// Problem constants (B=16, D=128, H=32, W=32, K=8192)
#define D 128
#define HW 1024
#define NROWS 16384
#define K 8192
#define NU 32   // 64-col units per block (2048-col k-split / 64)

// d_out layout (float offsets): z_q_st | indices | new_codebook | new_count | new_weight
#define OUT0 0
#define OUT1 2097152
#define OUT2 2113536
#define OUT3 3162112
#define OUT4 3170304

// d_ws layout (byte offsets)
#define WS_CNORM   0         // f32[8192]
#define WS_PACKED  32768     // u64[16384]
#define WS_CNT     163840    // u32[8192]
#define WS_DONE    196608    // u32[128]

typedef __attribute__((ext_vector_type(8))) _Float16 half8;
typedef __attribute__((ext_vector_type(16))) float f32x16;
typedef unsigned short u16;
typedef unsigned int u32;
typedef unsigned long long u64;

// ---- async global->LDS, 16B per lane (dst = wave-uniform base + lane*16) ----
__device__ __forceinline__ void gld16(const u16* gsrc, u16* ldst) {
    __builtin_amdgcn_global_load_lds(
        (const __attribute__((address_space(1))) unsigned int*)gsrc,
        (__attribute__((address_space(3))) unsigned int*)ldst,
        16, 0, 0);
}

// ---- prep: cb fp16 hi/lo split + cnorm + zero dw/cnt/done + packed init ----
// B layout: [unit g(128)][ Bh: [kk(16)][col(64)][j(8)] | Bl: same ] (32 KiB/unit)
__global__ __launch_bounds__(256) void k_prep(const float* __restrict__ cb,
                                              u16* __restrict__ Bg,
                                              float* __restrict__ cnorm,
                                              u64* __restrict__ packed,
                                              u32* __restrict__ cnt,
                                              u32* __restrict__ done,
                                              float* __restrict__ dw) {
    const int tid = threadIdx.x;
    int kk = tid & 15;
    int k = blockIdx.x * 16 + (tid >> 4);
    const float* src = cb + (size_t)k * D + kk * 8;
    half8 h, l;
    float s = 0.f;
#pragma unroll
    for (int j = 0; j < 8; ++j) {
        float v = src[j];
        s += v * v;
        _Float16 hv = (_Float16)v;              // RN f32->f16
        _Float16 lv = (_Float16)(v - (float)hv);
        h[j] = hv;
        l[j] = lv;
    }
    int g = k >> 6, col = k & 63;
    size_t offH = (size_t)g * 16384 + ((size_t)kk * 64 + col) * 8;
    *(half8*)((_Float16*)Bg + offH) = h;
    *(half8*)((_Float16*)Bg + offH + 8192) = l;
#pragma unroll
    for (int off = 8; off > 0; off >>= 1) s += __shfl_down(s, off);
    if (kk == 0) cnorm[k] = s;
    // zero dw: 512 blocks x 256 thr x 8 floats = K*D exactly
    float4 z4 = {0.f, 0.f, 0.f, 0.f};
    size_t zi = ((size_t)blockIdx.x * 256 + tid) * 8;
    *(float4*)(dw + zi) = z4;
    *(float4*)(dw + zi + 4) = z4;
    int gid = blockIdx.x * 256 + tid;
    if (gid < NROWS) packed[gid] = ~0ull;       // +inf sentinel
    if (gid < K) cnt[gid] = 0u;
    if (gid < 128) done[gid] = 0u;
}

// ---- main: inline A-split + 3-pass fp16-split GEMM + argmin + winner tail ----
// grid: 128 rowgroups (128 rows) x 4 ksplits = 512 blocks = 2/CU; 512 thr =
// 8 waves (wy 0..3 x wx 0..1); wave = 32 rows x 32 cols, A-frags in regs
// (64 VGPR, split in-kernel from z_e). B staged in 32 KiB units, 2x32 KiB
// dbuf; prefetch in flight across raw s_barrier via vmcnt(4). 16 waves/CU.
// After atomicMin, the LAST of the 4 ksplit siblings (done-counter) runs the
// scatter tail for its 128 rows: indices, counts, z_q_st, dw atomics —
// overlapped with other rowgroups' argmin work.
__global__ __launch_bounds__(512, 4) void k_argmin_tail(
        const float* __restrict__ z_e, const float* __restrict__ cb,
        const u16* __restrict__ Bg, const float* __restrict__ cnorm,
        u64* __restrict__ packed, float* __restrict__ out0,
        float* __restrict__ out1, u32* __restrict__ cnt,
        u32* __restrict__ done, float* __restrict__ dw) {
    __shared__ u16 lds[2][16384];               // 2 x 32 KiB
    __shared__ u32 winflag;

    const int tid = threadIdx.x;
    const int ln  = tid & 63;
    const int l31 = ln & 31;
    const int lh  = ln >> 5;                    // k-half select within frag
    const int wv  = tid >> 6;                   // 0..7
    const int wy  = wv & 3;                     // row band 0..3
    const int wx  = wv >> 2;                    // col half 0..1

    const int rg = blockIdx.x >> 2;             // 128 rowgroups x 128 rows
    const int k0 = (blockIdx.x & 3) * 2048;     // col split
    const int g0 = k0 >> 6;                     // first 64-col B-unit

    // ---- inline load & fp16-split of this wave's A rows (r6-proven) ----
    // frag dim for chunk ks: ks*16 + lh*8 + j  (matches B kk = ks*2+lh)
    const int rowA = rg * 128 + wy * 32 + l31;
    const float* za = z_e + (size_t)(rowA >> 10) * (D * HW) + (rowA & 1023);
    half8 Ah[8], Al[8];
#pragma unroll
    for (int ks = 0; ks < 8; ++ks) {
        half8 h, l;
#pragma unroll
        for (int j = 0; j < 8; ++j) {
            float v = za[(size_t)(ks * 16 + lh * 8 + j) * HW];
            _Float16 hv = (_Float16)v;
            _Float16 lv = (_Float16)(v - (float)hv);
            h[j] = hv;
            l[j] = lv;
        }
        Ah[ks] = h;
        Al[ks] = l;
    }

    // ---- stage unit 0 (32 KiB, 4 gld16/thread) ----
    {
        const u16* src = Bg + (size_t)g0 * 16384;
#pragma unroll
        for (int r = 0; r < 4; ++r)
            gld16(src + ((size_t)r * 512 + tid) * 8, lds[0] + (r * 512 + tid) * 8);
    }

    float minv[16];
    int   mini[16];
#pragma unroll
    for (int r = 0; r < 16; ++r) { minv[r] = INFINITY; mini[r] = 0; }

    const int bo_base = wx * 32 + l31;

#pragma unroll 1
    for (int u = 0; u < NU; ++u) {
        const int colv = k0 + u * 64 + wx * 32 + l31;
        float cn0 = cnorm[colv];

        if (u + 1 < NU) {
            const u16* src = Bg + (size_t)(g0 + u + 1) * 16384;
            u16* dst = lds[(u + 1) & 1];
#pragma unroll
            for (int r = 0; r < 4; ++r)
                gld16(src + ((size_t)r * 512 + tid) * 8, dst + (r * 512 + tid) * 8);
            // wait for *this* unit's stage; next unit's 4 loads stay in flight
            asm volatile("s_waitcnt vmcnt(4)" ::: "memory");
        } else {
            asm volatile("s_waitcnt vmcnt(0)" ::: "memory");
        }
        asm volatile("s_barrier" ::: "memory");

        const _Float16* bh = (const _Float16*)lds[u & 1];
        const _Float16* bl = bh + 8192;
        f32x16 acc = {};
#pragma unroll
        for (int ks = 0; ks < 8; ++ks) {
            const int bo = ((ks * 2 + lh) * 64 + bo_base) * 8;
            half8 vbl = *(const half8*)(bl + bo);
            half8 vbh = *(const half8*)(bh + bo);
            acc = __builtin_amdgcn_mfma_f32_32x32x16_f16(Ah[ks], vbl, acc, 0, 0, 0);
            acc = __builtin_amdgcn_mfma_f32_32x32x16_f16(Ah[ks], vbh, acc, 0, 0, 0);
            acc = __builtin_amdgcn_mfma_f32_32x32x16_f16(Al[ks], vbh, acc, 0, 0, 0);
        }

        // fold dist = cnorm - 2*dot into running argmin
#pragma unroll
        for (int r = 0; r < 16; ++r) {
            float d0 = fmaf(-2.0f, acc[r], cn0);
            if (d0 < minv[r]) { minv[r] = d0; mini[r] = colv; }
        }
        // all waves done reading lds[u&1] before next iter's prefetch overwrite
        asm volatile("s_barrier" ::: "memory");
    }

    // ---- reduce across the 32 l31-lanes sharing each output row ----
#pragma unroll
    for (int r = 0; r < 16; ++r) {
        float v = minv[r];
        int ix = mini[r];
#pragma unroll
        for (int off = 1; off < 32; off <<= 1) {
            float v2 = __shfl_xor(v, off);
            int i2 = __shfl_xor(ix, off);
            if (v2 < v || (v2 == v && i2 < ix)) { v = v2; ix = i2; }
        }
        if (l31 == 0) {
            // C/D row map (m74/m101): row32 = (r&3) + 8*(r>>2) + 4*lh
            int row = rg * 128 + wy * 32 + 4 * lh + (r & 3) + 8 * (r >> 2);
            unsigned int uenc = __float_as_uint(v);
            uenc = (uenc & 0x80000000u) ? ~uenc : (uenc | 0x80000000u);  // monotonic
            u64 pk = ((u64)uenc << 13) | (u64)(unsigned)ix;
            atomicMin(&packed[row], pk);
        }
    }

    // ---- last-arriver fixup: 4th ksplit sibling finalizes this rowgroup ----
    __threadfence();                            // drain + make atomics visible
    __syncthreads();
    if (tid == 0) winflag = atomicAdd(&done[rg], 1u);
    __syncthreads();
    if (winflag != 3u) return;

    __threadfence();                            // acquire siblings' atomics
    int* idxS = (int*)&lds[0][0];               // LDS reuse (argmin phase done)
    const int n0 = rg * 128;
    const int bb = n0 >> 10, p0 = n0 & 1023;

    if (tid < 128) {
        u64 p = __hip_atomic_load(&packed[n0 + tid], __ATOMIC_RELAXED,
                                  __HIP_MEMORY_SCOPE_AGENT);
        int ix = (int)(p & 0x1FFFull);
        idxS[tid] = ix;
        out1[n0 + tid] = (float)ix;
        atomicAdd(&cnt[ix], 1u);
    }
    __syncthreads();

    const float* zb = z_e + (size_t)bb * (D * HW) + p0;
    float* ob = out0 + (size_t)bb * (D * HW) + p0;

    // z_q_st: coalesced (r contiguous per wave); warms the z tile in L1/L2
    for (int i = tid; i < 128 * D; i += 512) {
        int d = i >> 7, r = i & 127;
        float z = zb[(size_t)d * HW + r];
        float c = cb[(size_t)idxS[r] * D + d];
        ob[(size_t)d * HW + r] = z + (c - z);
    }
    // dw: d contiguous per wave -> coalesced atomic runs; z re-reads hit cache
    for (int i = tid; i < 128 * D; i += 512) {
        int r = i >> 7, d = i & 127;
        atomicAdd(&dw[(size_t)idxS[r] * D + d], zb[(size_t)d * HW + r]);
    }
}

// ---- final: EMA update (reads cnt/dw finalized by kernel 2) ----
__global__ __launch_bounds__(256) void k_final(const u32* __restrict__ cnt,
                                               const float* __restrict__ ema_count,
                                               const float* __restrict__ ema_weight,
                                               float* __restrict__ out2,
                                               float* __restrict__ out3,
                                               float* __restrict__ out4) {
    int gid = blockIdx.x * 256 + threadIdx.x;   // over K*D
    int k = gid >> 7, d = gid & 127;
    float nc = 0.99f * ema_count[k] + 0.01f * (float)cnt[k];
    float nw = 0.99f * ema_weight[gid] + 0.01f * out4[gid];
    out4[gid] = nw;
    out2[gid] = nw / fmaxf(nc, 1.0f);
    if (d == 0) out3[k] = nc;
}

extern "C" void kernel_launch(void* const* d_in, const int* in_sizes, int n_in,
                              void* d_out, int out_size, void* d_ws, size_t ws_size,
                              hipStream_t stream) {
    const float* z_e        = (const float*)d_in[0];
    const float* cb         = (const float*)d_in[1];
    const float* ema_count  = (const float*)d_in[2];
    const float* ema_weight = (const float*)d_in[3];
    float* out = (float*)d_out;
    char* ws = (char*)d_ws;

    float* cnorm  = (float*)(ws + WS_CNORM);
    u64*   packed = (u64*)(ws + WS_PACKED);
    u32*   cnt    = (u32*)(ws + WS_CNT);
    u32*   done   = (u32*)(ws + WS_DONE);

    // fp16-split B lives in out2 (4 MB) until k_final overwrites it.
    u16* Bg = (u16*)(out + OUT2);

    k_prep       <<<K / 16,        256, 0, stream>>>(cb, Bg, cnorm, packed, cnt,
                                                     done, out + OUT4);
    k_argmin_tail<<<512,           512, 0, stream>>>(z_e, cb, Bg, cnorm, packed,
                                                     out + OUT0, out + OUT1, cnt,
                                                     done, out + OUT4);
    k_final      <<<(K * D) / 256, 256, 0, stream>>>(cnt, ema_count, ema_weight,
                                                     out + OUT2, out + OUT3,
                                                     out + OUT4);
}